// Round 3
// baseline (1709.198 us; speedup 1.0000x reference)
//
#include <hip/hip_runtime.h>
#include <cstdint>
#include <cstddef>

// -------- GCN 2-layer: out = A_norm @ prelu(A_norm @ (x W1) + b1) @ W2 + b2 --------
// A_norm = D^-1/2 (A + I) D^-1/2, deg = in-degree + 1 (PyG GCNConv default).
// NOTE: harness passes integer inputs as int32 — edge_index is const int*,
// laid out [2][E] flat: src = ei[e], dst = ei[E + e].
// CSR built once per call (count/scan/fill); edge weight dis[s]*dis[d] on the fly.
// Ping-pong: sgemm(x)->T(ws), agg(T)->d_out, sgemm(d_out)->T, agg(T)->d_out.

#define IN_C 256

__global__ __launch_bounds__(256) void count_kernel(const int* __restrict__ ei,
                                                    int* __restrict__ cnt, int E) {
    int e = blockIdx.x * 256 + threadIdx.x;
    if (e < E) {
        int d = ei[(size_t)E + e];
        atomicAdd(&cnt[d], 1);
    }
}

__global__ __launch_bounds__(256) void dis_kernel(const int* __restrict__ cnt,
                                                  float* __restrict__ dis, int N) {
    int i = blockIdx.x * 256 + threadIdx.x;
    if (i < N) dis[i] = rsqrtf((float)(cnt[i] + 1));  // deg >= 1 always (self-loop)
}

// block scans 1024 counts (256 threads x 4); writes local-exclusive prefix + block total
__global__ __launch_bounds__(256) void scanA(const int* __restrict__ cnt,
                                             int* __restrict__ row_ptr,
                                             int* __restrict__ partials, int N) {
    __shared__ int sdata[256];
    int tid = threadIdx.x;
    int base = blockIdx.x * 1024 + tid * 4;
    int v[4]; int s = 0;
#pragma unroll
    for (int i = 0; i < 4; i++) { int idx = base + i; v[i] = (idx < N) ? cnt[idx] : 0; s += v[i]; }
    sdata[tid] = s;
    __syncthreads();
    for (int off = 1; off < 256; off <<= 1) {
        int add = (tid >= off) ? sdata[tid - off] : 0;
        __syncthreads();
        sdata[tid] += add;
        __syncthreads();
    }
    int run = sdata[tid] - s;  // exclusive within block
#pragma unroll
    for (int i = 0; i < 4; i++) {
        int idx = base + i;
        if (idx < N) row_ptr[idx] = run;
        run += v[i];
    }
    if (tid == 255) partials[blockIdx.x] = sdata[255];
}

__global__ void scanB(int* __restrict__ partials, int* __restrict__ row_ptr, int nb, int N) {
    if (threadIdx.x == 0 && blockIdx.x == 0) {
        int run = 0;
        for (int b = 0; b < nb; b++) { int t = partials[b]; partials[b] = run; run += t; }
        row_ptr[N] = run;  // == E
    }
}

__global__ __launch_bounds__(256) void scanC(int* __restrict__ row_ptr, int* __restrict__ cursor,
                                             const int* __restrict__ partials, int N) {
    int i = blockIdx.x * 256 + threadIdx.x;
    if (i < N) {
        int v = row_ptr[i] + partials[i >> 10];
        row_ptr[i] = v;
        cursor[i] = v;
    }
}

__global__ __launch_bounds__(256) void fill_kernel(const int* __restrict__ ei,
                                                   int* __restrict__ cursor,
                                                   int* __restrict__ csr_src, int E) {
    int e = blockIdx.x * 256 + threadIdx.x;
    if (e < E) {
        int s = ei[e];
        int d = ei[(size_t)E + e];
        int pos = atomicAdd(&cursor[d], 1);
        csr_src[pos] = s;
    }
}

// C[M x 256] = A[M x 256] @ B[256 x 256], fp32, 64x64 tile, 4x4 per thread
__global__ __launch_bounds__(256) void sgemm(const float* __restrict__ A,
                                             const float* __restrict__ B,
                                             float* __restrict__ C, int M) {
    __shared__ float As[64][17];
    __shared__ float Bs[16][64];
    int tid = threadIdx.x;
    int bx = blockIdx.x & 3;        // col tile (256/64)
    int by = blockIdx.x >> 2;       // row tile
    int tx = tid & 15, ty = tid >> 4;
    int row0 = by * 64, col0 = bx * 64;
    float acc[4][4] = {};
    for (int k0 = 0; k0 < 256; k0 += 16) {
        int ar = tid >> 2, ak = (tid & 3) * 4;
        int grow = row0 + ar;
        float4 av = make_float4(0.f, 0.f, 0.f, 0.f);
        if (grow < M) av = *(const float4*)&A[(size_t)grow * 256 + k0 + ak];
        As[ar][ak + 0] = av.x; As[ar][ak + 1] = av.y; As[ar][ak + 2] = av.z; As[ar][ak + 3] = av.w;
        int br = tid >> 4, bc = (tid & 15) * 4;
        float4 bv = *(const float4*)&B[(size_t)(k0 + br) * 256 + col0 + bc];
        *(float4*)&Bs[br][bc] = bv;
        __syncthreads();
#pragma unroll
        for (int kk = 0; kk < 16; ++kk) {
            float a[4], b[4];
#pragma unroll
            for (int i = 0; i < 4; i++) a[i] = As[ty * 4 + i][kk];
#pragma unroll
            for (int j = 0; j < 4; j++) b[j] = Bs[kk][tx * 4 + j];
#pragma unroll
            for (int i = 0; i < 4; i++)
#pragma unroll
                for (int j = 0; j < 4; j++) acc[i][j] += a[i] * b[j];
        }
        __syncthreads();
    }
#pragma unroll
    for (int i = 0; i < 4; i++) {
        int gr = row0 + ty * 4 + i;
        if (gr < M) {
            float4 v = make_float4(acc[i][0], acc[i][1], acc[i][2], acc[i][3]);
            *(float4*)&C[(size_t)gr * 256 + col0 + tx * 4] = v;
        }
    }
}

// one wave per node; lane handles 4 consecutive columns (float4).
// edge weight dis[s]*dis[n] computed in-loop (dis[s] is wave-uniform -> broadcast).
__global__ __launch_bounds__(256) void aggregate(const float* __restrict__ h,
                                                 const int* __restrict__ row_ptr,
                                                 const int* __restrict__ csr_src,
                                                 const float* __restrict__ dis,
                                                 const float* __restrict__ bias,
                                                 const float* __restrict__ alpha_p,
                                                 float* __restrict__ out, int N, int prelu) {
    int wave = threadIdx.x >> 6;
    int lane = threadIdx.x & 63;
    int n = blockIdx.x * 4 + wave;
    if (n >= N) return;
    int c = lane * 4;
    float dn = dis[n];
    float selfw = dn * dn;
    float4 acc = *(const float4*)&h[(size_t)n * 256 + c];
    acc.x *= selfw; acc.y *= selfw; acc.z *= selfw; acc.w *= selfw;
    int e0 = row_ptr[n], e1 = row_ptr[n + 1];
    for (int e = e0; e < e1; ++e) {
        int s = csr_src[e];
        float w = dis[s] * dn;
        float4 v = *(const float4*)&h[(size_t)s * 256 + c];
        acc.x += w * v.x; acc.y += w * v.y; acc.z += w * v.z; acc.w += w * v.w;
    }
    float4 bv = *(const float4*)&bias[c];
    acc.x += bv.x; acc.y += bv.y; acc.z += bv.z; acc.w += bv.w;
    if (prelu) {
        float al = *alpha_p;
        acc.x = acc.x >= 0.f ? acc.x : al * acc.x;
        acc.y = acc.y >= 0.f ? acc.y : al * acc.y;
        acc.z = acc.z >= 0.f ? acc.z : al * acc.z;
        acc.w = acc.w >= 0.f ? acc.w : al * acc.w;
    }
    *(float4*)&out[(size_t)n * 256 + c] = acc;
}

extern "C" void kernel_launch(void* const* d_in, const int* in_sizes, int n_in,
                              void* d_out, int out_size, void* d_ws, size_t ws_size,
                              hipStream_t stream) {
    const float* x = (const float*)d_in[0];
    const int* ei = (const int*)d_in[1];          // int32 (harness converts int64 -> int32)
    const float* W1 = (const float*)d_in[2];
    const float* b1 = (const float*)d_in[3];
    const float* W2 = (const float*)d_in[4];
    const float* b2 = (const float*)d_in[5];
    const float* alpha = (const float*)d_in[6];
    int N = in_sizes[0] / IN_C;
    int E = in_sizes[1] / 2;

    char* ws = (char*)d_ws;
    size_t off = 0;
    auto alloc = [&](size_t bytes) {
        void* p = ws + off;
        off = (off + bytes + 255) & ~(size_t)255;
        return p;
    };
    int* cnt      = (int*)alloc((size_t)N * 4);
    int* row_ptr  = (int*)alloc(((size_t)N + 1) * 4);
    int* cursor   = (int*)alloc((size_t)N * 4);
    int* partials = (int*)alloc(1024 * 4);
    float* dis    = (float*)alloc((size_t)N * 4);
    int* csr_src  = (int*)alloc((size_t)E * 4);
    float* T      = (float*)alloc((size_t)N * IN_C * 4);

    // Guard: if ws too small, do nothing -> clean absmax fail instead of fault.
    if (off > ws_size) return;

    hipMemsetAsync(cnt, 0, (size_t)N * 4, stream);

    int eb = (E + 255) / 256;
    int nb256 = (N + 255) / 256;
    int nb1024 = (N + 1023) / 1024;

    count_kernel<<<eb, 256, 0, stream>>>(ei, cnt, E);
    dis_kernel<<<nb256, 256, 0, stream>>>(cnt, dis, N);
    scanA<<<nb1024, 256, 0, stream>>>(cnt, row_ptr, partials, N);
    scanB<<<1, 64, 0, stream>>>(partials, row_ptr, nb1024, N);
    scanC<<<nb256, 256, 0, stream>>>(row_ptr, cursor, partials, N);
    fill_kernel<<<eb, 256, 0, stream>>>(ei, cursor, csr_src, E);

    float* outf = (float*)d_out;
    int mtiles = (N + 63) / 64;
    sgemm<<<mtiles * 4, 256, 0, stream>>>(x, W1, T, N);                 // T = x@W1
    aggregate<<<(N + 3) / 4, 256, 0, stream>>>(T, row_ptr, csr_src, dis, b1, alpha, outf, N, 1);
    sgemm<<<mtiles * 4, 256, 0, stream>>>(outf, W2, T, N);              // T = d_out@W2
    aggregate<<<(N + 3) / 4, 256, 0, stream>>>(T, row_ptr, csr_src, dis, b2, alpha, outf, N, 0);
}

// Round 4
// 1576.951 us; speedup vs baseline: 1.0839x; 1.0839x over previous
//
#include <hip/hip_runtime.h>
#include <cstdint>
#include <cstddef>

// -------- GCN 2-layer: out = A_norm @ prelu(A_norm @ (x W1) + b1) @ W2 + b2 --------
// A_norm = D^-1/2 (A + I) D^-1/2, deg = in-degree + 1 (PyG GCNConv default).
// edge_index arrives as int32 [2][E]: src = ei[e], dst = ei[E + e].
// Pipeline: CSR build; W -> WT hi/lo bf16 (once); MFMA GEMM (hi/lo split, fp32-accurate)
// writing T as bf16; aggregate gathers bf16 rows (512 B/row) with fp32 accum.
// Ping-pong: gemm(x)->T, agg(T)->d_out, gemm(d_out)->T, agg(T)->d_out.  ws ~66 MB.

#define IN_C 256

typedef __attribute__((ext_vector_type(8))) short bf16x8;
typedef __attribute__((ext_vector_type(4))) float f32x4;

__device__ __forceinline__ ushort f2bf(float x) {
    union { float f; uint32_t u; } v; v.f = x;
    uint32_t r = v.u + 0x7FFF + ((v.u >> 16) & 1);   // round-to-nearest-even
    return (ushort)(r >> 16);
}
__device__ __forceinline__ float bf2f(ushort b) {
    union { uint32_t u; float f; } v; v.u = ((uint32_t)b) << 16;
    return v.f;
}

// ---------------- CSR build ----------------
__global__ __launch_bounds__(256) void count_kernel(const int* __restrict__ ei,
                                                    int* __restrict__ cnt, int E) {
    int e = blockIdx.x * 256 + threadIdx.x;
    if (e < E) atomicAdd(&cnt[ei[(size_t)E + e]], 1);
}

__global__ __launch_bounds__(256) void dis_kernel(const int* __restrict__ cnt,
                                                  float* __restrict__ dis, int N) {
    int i = blockIdx.x * 256 + threadIdx.x;
    if (i < N) dis[i] = rsqrtf((float)(cnt[i] + 1));  // deg >= 1 (self-loop)
}

__global__ __launch_bounds__(256) void scanA(const int* __restrict__ cnt,
                                             int* __restrict__ row_ptr,
                                             int* __restrict__ partials, int N) {
    __shared__ int sdata[256];
    int tid = threadIdx.x;
    int base = blockIdx.x * 1024 + tid * 4;
    int v[4]; int s = 0;
#pragma unroll
    for (int i = 0; i < 4; i++) { int idx = base + i; v[i] = (idx < N) ? cnt[idx] : 0; s += v[i]; }
    sdata[tid] = s;
    __syncthreads();
    for (int off = 1; off < 256; off <<= 1) {
        int add = (tid >= off) ? sdata[tid - off] : 0;
        __syncthreads();
        sdata[tid] += add;
        __syncthreads();
    }
    int run = sdata[tid] - s;
#pragma unroll
    for (int i = 0; i < 4; i++) {
        int idx = base + i;
        if (idx < N) row_ptr[idx] = run;
        run += v[i];
    }
    if (tid == 255) partials[blockIdx.x] = sdata[255];
}

__global__ void scanB(int* __restrict__ partials, int* __restrict__ row_ptr, int nb, int N) {
    if (threadIdx.x == 0 && blockIdx.x == 0) {
        int run = 0;
        for (int b = 0; b < nb; b++) { int t = partials[b]; partials[b] = run; run += t; }
        row_ptr[N] = run;
    }
}

__global__ __launch_bounds__(256) void scanC(int* __restrict__ row_ptr, int* __restrict__ cursor,
                                             const int* __restrict__ partials, int N) {
    int i = blockIdx.x * 256 + threadIdx.x;
    if (i < N) {
        int v = row_ptr[i] + partials[i >> 10];
        row_ptr[i] = v;
        cursor[i] = v;
    }
}

__global__ __launch_bounds__(256) void fill_kernel(const int* __restrict__ ei,
                                                   int* __restrict__ cursor,
                                                   int* __restrict__ csr_src, int E) {
    int e = blockIdx.x * 256 + threadIdx.x;
    if (e < E) {
        int s = ei[e];
        int d = ei[(size_t)E + e];
        int pos = atomicAdd(&cursor[d], 1);
        csr_src[pos] = s;
    }
}

// ---------------- weight prep: W[k][n] f32 -> WT[n][k] hi/lo bf16 ----------------
__global__ __launch_bounds__(256) void prep_w(const float* __restrict__ W,
                                              ushort* __restrict__ WTh,
                                              ushort* __restrict__ WTl) {
    int id = blockIdx.x * 256 + threadIdx.x;   // 65536
    int n = id >> 8, k = id & 255;
    float w = W[k * 256 + n];
    ushort h = f2bf(w);
    WTh[id] = h;                                // WT[n][k], coalesced writes
    WTl[id] = f2bf(w - bf2f(h));
}

// ---------------- MFMA GEMM: C(bf16)[M][256] = A(f32)[M][256] @ W ----------------
// W given as WT[n][k] hi/lo bf16. Split-bf16 (3 MFMA terms) ~ fp32 accuracy.
// Tile 128x64, K-step 64, 4 waves (2x2), per-wave 64x32 = 4x2 16x16 frags.
__global__ __launch_bounds__(256) void gemm_bf16(const float* __restrict__ A,
                                                 const ushort* __restrict__ WTh,
                                                 const ushort* __restrict__ WTl,
                                                 ushort* __restrict__ C, int M) {
    __shared__ ushort As_h[128][72], As_l[128][72];   // +8 pad: 2-way conflicts only
    __shared__ ushort Bs_h[64][72],  Bs_l[64][72];
    int tid = threadIdx.x;
    int bx = blockIdx.x & 3, by = blockIdx.x >> 2;
    int row0 = by * 128, col0 = bx * 64;
    int wid = tid >> 6, lane = tid & 63;
    int wm = wid >> 1, wn = wid & 1;
    int lrow = lane & 15, lk = (lane >> 4) * 8;

    f32x4 acc[4][2];
#pragma unroll
    for (int i = 0; i < 4; i++)
#pragma unroll
        for (int j = 0; j < 2; j++) acc[i][j] = (f32x4)0.f;

    for (int k0 = 0; k0 < 256; k0 += 64) {
        // stage A 128x64 f32 -> hi/lo bf16 LDS
#pragma unroll
        for (int i = 0; i < 8; ++i) {
            int f = tid + i * 256;            // 2048 float4 units
            int r = f >> 4, c4 = (f & 15) * 4;
            int gr = row0 + r;
            float4 av = make_float4(0.f, 0.f, 0.f, 0.f);
            if (gr < M) av = *(const float4*)&A[(size_t)gr * 256 + k0 + c4];
            ushort h0 = f2bf(av.x), h1 = f2bf(av.y), h2 = f2bf(av.z), h3 = f2bf(av.w);
            *(ushort4*)&As_h[r][c4] = make_ushort4(h0, h1, h2, h3);
            *(ushort4*)&As_l[r][c4] = make_ushort4(f2bf(av.x - bf2f(h0)), f2bf(av.y - bf2f(h1)),
                                                   f2bf(av.z - bf2f(h2)), f2bf(av.w - bf2f(h3)));
        }
        // stage B (WT rows col0..col0+63, k-cols k0..k0+63)
#pragma unroll
        for (int i = 0; i < 4; ++i) {
            int u = tid + i * 256;            // 1024 short4 units per plane
            int r = u >> 4, c4 = (u & 15) * 4;
            *(ushort4*)&Bs_h[r][c4] = *(const ushort4*)&WTh[(size_t)(col0 + r) * 256 + k0 + c4];
            *(ushort4*)&Bs_l[r][c4] = *(const ushort4*)&WTl[(size_t)(col0 + r) * 256 + k0 + c4];
        }
        __syncthreads();
#pragma unroll
        for (int kk = 0; kk < 2; ++kk) {
            int kb = kk * 32 + lk;
            bf16x8 bh[2], bl[2];
#pragma unroll
            for (int j = 0; j < 2; ++j) {
                bh[j] = *(bf16x8*)&Bs_h[wn * 32 + j * 16 + lrow][kb];
                bl[j] = *(bf16x8*)&Bs_l[wn * 32 + j * 16 + lrow][kb];
            }
#pragma unroll
            for (int i = 0; i < 4; ++i) {
                bf16x8 ah = *(bf16x8*)&As_h[wm * 64 + i * 16 + lrow][kb];
                bf16x8 al = *(bf16x8*)&As_l[wm * 64 + i * 16 + lrow][kb];
#pragma unroll
                for (int j = 0; j < 2; ++j) {
                    acc[i][j] = __builtin_amdgcn_mfma_f32_16x16x32_bf16(ah, bh[j], acc[i][j], 0, 0, 0);
                    acc[i][j] = __builtin_amdgcn_mfma_f32_16x16x32_bf16(ah, bl[j], acc[i][j], 0, 0, 0);
                    acc[i][j] = __builtin_amdgcn_mfma_f32_16x16x32_bf16(al, bh[j], acc[i][j], 0, 0, 0);
                }
            }
        }
        __syncthreads();
    }
    // C/D layout (m89): col = lane&15, row = (lane>>4)*4 + reg
    int rb = (lane >> 4) * 4;
#pragma unroll
    for (int i = 0; i < 4; ++i)
#pragma unroll
        for (int j = 0; j < 2; ++j)
#pragma unroll
            for (int r = 0; r < 4; ++r) {
                int grow = row0 + wm * 64 + i * 16 + rb + r;
                int gcol = col0 + wn * 32 + j * 16 + lrow;
                if (grow < M) C[(size_t)grow * 256 + gcol] = f2bf(acc[i][j][r]);
            }
}

// ---------------- aggregate: out[n] = dn^2*T[n] + sum_e dis[s]*dn*T[s] + b ----------------
// one wave per node; lane covers 4 cols via bf16x4 (8 B) gather; fp32 accum.
__global__ __launch_bounds__(256) void aggregate_bf16(const ushort* __restrict__ T,
                                                      const int* __restrict__ row_ptr,
                                                      const int* __restrict__ csr_src,
                                                      const float* __restrict__ dis,
                                                      const float* __restrict__ bias,
                                                      const float* __restrict__ alpha_p,
                                                      float* __restrict__ out, int N, int prelu) {
    int wave = threadIdx.x >> 6;
    int lane = threadIdx.x & 63;
    int n = blockIdx.x * 4 + wave;
    if (n >= N) return;
    int c = lane * 4;
    float dn = dis[n];
    float sw = dn * dn;
    ushort4 sv = *(const ushort4*)&T[(size_t)n * 256 + c];
    float4 acc;
    acc.x = sw * bf2f(sv.x); acc.y = sw * bf2f(sv.y);
    acc.z = sw * bf2f(sv.z); acc.w = sw * bf2f(sv.w);
    int e0 = row_ptr[n], e1 = row_ptr[n + 1];
    for (int e = e0; e < e1; ++e) {
        int s = csr_src[e];
        float w = dis[s] * dn;
        ushort4 v = *(const ushort4*)&T[(size_t)s * 256 + c];
        acc.x += w * bf2f(v.x); acc.y += w * bf2f(v.y);
        acc.z += w * bf2f(v.z); acc.w += w * bf2f(v.w);
    }
    float4 bv = *(const float4*)&bias[c];
    acc.x += bv.x; acc.y += bv.y; acc.z += bv.z; acc.w += bv.w;
    if (prelu) {
        float al = *alpha_p;
        acc.x = acc.x >= 0.f ? acc.x : al * acc.x;
        acc.y = acc.y >= 0.f ? acc.y : al * acc.y;
        acc.z = acc.z >= 0.f ? acc.z : al * acc.z;
        acc.w = acc.w >= 0.f ? acc.w : al * acc.w;
    }
    *(float4*)&out[(size_t)n * 256 + c] = acc;
}

extern "C" void kernel_launch(void* const* d_in, const int* in_sizes, int n_in,
                              void* d_out, int out_size, void* d_ws, size_t ws_size,
                              hipStream_t stream) {
    const float* x = (const float*)d_in[0];
    const int* ei = (const int*)d_in[1];          // int32 (harness converts int64 -> int32)
    const float* W1 = (const float*)d_in[2];
    const float* b1 = (const float*)d_in[3];
    const float* W2 = (const float*)d_in[4];
    const float* b2 = (const float*)d_in[5];
    const float* alpha = (const float*)d_in[6];
    int N = in_sizes[0] / IN_C;
    int E = in_sizes[1] / 2;

    char* ws = (char*)d_ws;
    size_t off = 0;
    auto alloc = [&](size_t bytes) {
        void* p = ws + off;
        off = (off + bytes + 255) & ~(size_t)255;
        return p;
    };
    int* cnt      = (int*)alloc((size_t)N * 4);
    int* row_ptr  = (int*)alloc(((size_t)N + 1) * 4);
    int* cursor   = (int*)alloc((size_t)N * 4);
    int* partials = (int*)alloc(1024 * 4);
    float* dis    = (float*)alloc((size_t)N * 4);
    int* csr_src  = (int*)alloc((size_t)E * 4);
    ushort* T     = (ushort*)alloc((size_t)N * IN_C * 2);    // bf16
    ushort* W1h   = (ushort*)alloc(256 * 256 * 2);
    ushort* W1l   = (ushort*)alloc(256 * 256 * 2);
    ushort* W2h   = (ushort*)alloc(256 * 256 * 2);
    ushort* W2l   = (ushort*)alloc(256 * 256 * 2);

    if (off > ws_size) return;   // clean fail instead of fault if ws too small

    hipMemsetAsync(cnt, 0, (size_t)N * 4, stream);

    int eb = (E + 255) / 256;
    int nb256 = (N + 255) / 256;
    int nb1024 = (N + 1023) / 1024;

    count_kernel<<<eb, 256, 0, stream>>>(ei, cnt, E);
    dis_kernel<<<nb256, 256, 0, stream>>>(cnt, dis, N);
    scanA<<<nb1024, 256, 0, stream>>>(cnt, row_ptr, partials, N);
    scanB<<<1, 64, 0, stream>>>(partials, row_ptr, nb1024, N);
    scanC<<<nb256, 256, 0, stream>>>(row_ptr, cursor, partials, N);
    fill_kernel<<<eb, 256, 0, stream>>>(ei, cursor, csr_src, E);

    prep_w<<<256, 256, 0, stream>>>(W1, W1h, W1l);
    prep_w<<<256, 256, 0, stream>>>(W2, W2h, W2l);

    float* outf = (float*)d_out;
    int mtiles = (N + 127) / 128;
    gemm_bf16<<<mtiles * 4, 256, 0, stream>>>(x, W1h, W1l, T, N);      // T = x@W1 (bf16)
    aggregate_bf16<<<(N + 3) / 4, 256, 0, stream>>>(T, row_ptr, csr_src, dis, b1, alpha, outf, N, 1);
    gemm_bf16<<<mtiles * 4, 256, 0, stream>>>(outf, W2h, W2l, T, N);   // T = d_out@W2 (bf16)
    aggregate_bf16<<<(N + 3) / 4, 256, 0, stream>>>(T, row_ptr, csr_src, dis, b2, alpha, outf, N, 0);
}

// Round 5
// 1122.677 us; speedup vs baseline: 1.5224x; 1.4046x over previous
//
#include <hip/hip_runtime.h>
#include <cstdint>
#include <cstddef>

// -------- GCN 2-layer: out = A_norm @ prelu(A_norm @ (x W1) + b1) @ W2 + b2 --------
// A_norm = D^-1/2 (A + I) D^-1/2, deg = in-degree + 1 (PyG GCNConv default).
// edge_index arrives int32 [2][E]: src = ei[e], dst = ei[E + e].
//
// Key restructure vs round 4:
//  * dis folded into GEMM epilogue: T'[r] = dis[r]*(A@W)[r]  ->  aggregate is a pure
//    row-sum: out[n] = dis[n]*(T'[n] + sum_e T'[src_e]) + b. No per-edge weight loads.
//  * aggregate batches 64 edge indices per coalesced load, broadcasts via readlane,
//    unrolls x4 with 4 independent accumulators (4+ outstanding gathers).
//  * GEMM has NO LDS / NO barriers: per-wave 64x128 tile, hi/lo-split bf16 A and W
//    fragments loaded directly from global (fully coalesced; W is L2-resident).
//    A is pre-split once (split_x); layer-1 aggregate emits hi/lo planes directly.
//  * d_out hosts Xh/Hh plane + W split tables (dead before final write). ws ~116.4MB.

#define IN_C 256

typedef __attribute__((ext_vector_type(8))) short bf16x8;
typedef __attribute__((ext_vector_type(4))) float f32x4;

__device__ __forceinline__ ushort f2bf(float x) {
    union { float f; uint32_t u; } v; v.f = x;
    uint32_t r = v.u + 0x7FFF + ((v.u >> 16) & 1);   // round-to-nearest-even
    return (ushort)(r >> 16);
}
__device__ __forceinline__ float bf2f(ushort b) {
    union { uint32_t u; float f; } v; v.u = ((uint32_t)b) << 16;
    return v.f;
}

// ---------------- CSR build ----------------
__global__ __launch_bounds__(256) void count_kernel(const int* __restrict__ ei,
                                                    int* __restrict__ cnt, int E) {
    int e = blockIdx.x * 256 + threadIdx.x;
    if (e < E) atomicAdd(&cnt[ei[(size_t)E + e]], 1);
}

__global__ __launch_bounds__(256) void dis_kernel(const int* __restrict__ cnt,
                                                  float* __restrict__ dis, int N) {
    int i = blockIdx.x * 256 + threadIdx.x;
    if (i < N) dis[i] = rsqrtf((float)(cnt[i] + 1));  // deg >= 1 (self-loop)
}

__global__ __launch_bounds__(256) void scanA(const int* __restrict__ cnt,
                                             int* __restrict__ row_ptr,
                                             int* __restrict__ partials, int N) {
    __shared__ int sdata[256];
    int tid = threadIdx.x;
    int base = blockIdx.x * 1024 + tid * 4;
    int v[4]; int s = 0;
#pragma unroll
    for (int i = 0; i < 4; i++) { int idx = base + i; v[i] = (idx < N) ? cnt[idx] : 0; s += v[i]; }
    sdata[tid] = s;
    __syncthreads();
    for (int off = 1; off < 256; off <<= 1) {
        int add = (tid >= off) ? sdata[tid - off] : 0;
        __syncthreads();
        sdata[tid] += add;
        __syncthreads();
    }
    int run = sdata[tid] - s;
#pragma unroll
    for (int i = 0; i < 4; i++) {
        int idx = base + i;
        if (idx < N) row_ptr[idx] = run;
        run += v[i];
    }
    if (tid == 255) partials[blockIdx.x] = sdata[255];
}

__global__ void scanB(int* __restrict__ partials, int* __restrict__ row_ptr, int nb, int N) {
    if (threadIdx.x == 0 && blockIdx.x == 0) {
        int run = 0;
        for (int b = 0; b < nb; b++) { int t = partials[b]; partials[b] = run; run += t; }
        row_ptr[N] = run;
    }
}

// cursor may alias cnt (cnt is dead after scanA)
__global__ __launch_bounds__(256) void scanC(int* __restrict__ row_ptr, int* __restrict__ cursor,
                                             const int* __restrict__ partials, int N) {
    int i = blockIdx.x * 256 + threadIdx.x;
    if (i < N) {
        int v = row_ptr[i] + partials[i >> 10];
        row_ptr[i] = v;
        cursor[i] = v;
    }
}

__global__ __launch_bounds__(256) void fill_kernel(const int* __restrict__ ei,
                                                   int* __restrict__ cursor,
                                                   int* __restrict__ csr_src, int E) {
    int e = blockIdx.x * 256 + threadIdx.x;
    if (e < E) {
        int s = ei[e];
        int d = ei[(size_t)E + e];
        int pos = atomicAdd(&cursor[d], 1);
        csr_src[pos] = s;
    }
}

// ---------------- split fp32 -> hi/lo bf16 planes ----------------
__global__ __launch_bounds__(256) void split_x(const float* __restrict__ x,
                                               ushort* __restrict__ Xh,
                                               ushort* __restrict__ Xl, int total4) {
    int id = blockIdx.x * 256 + threadIdx.x;   // unit = 4 floats
    if (id >= total4) return;
    float4 v = ((const float4*)x)[id];
    ushort hx = f2bf(v.x), hy = f2bf(v.y), hz = f2bf(v.z), hw = f2bf(v.w);
    ((ushort4*)Xh)[id] = make_ushort4(hx, hy, hz, hw);
    ((ushort4*)Xl)[id] = make_ushort4(f2bf(v.x - bf2f(hx)), f2bf(v.y - bf2f(hy)),
                                      f2bf(v.z - bf2f(hz)), f2bf(v.w - bf2f(hw)));
}

// ---------------- weight prep: W[k][n] f32 -> WT[n][k] hi/lo bf16 ----------------
__global__ __launch_bounds__(256) void prep_w(const float* __restrict__ W,
                                              ushort* __restrict__ WTh,
                                              ushort* __restrict__ WTl) {
    int id = blockIdx.x * 256 + threadIdx.x;   // 65536
    int n = id >> 8, k = id & 255;
    float w = W[k * 256 + n];
    ushort h = f2bf(w);
    WTh[id] = h;
    WTl[id] = f2bf(w - bf2f(h));
}

// ---------------- no-LDS MFMA GEMM: T'(bf16)[M][256] = dis[r] * (A @ W) ----------------
// A given as Ah/Al bf16 planes [M][256]; W as WT[n][k] hi/lo bf16.
// One wave computes a 64x128 tile; fragments loaded directly from global.
__global__ __launch_bounds__(256, 2) void gemm_split(const ushort* __restrict__ Ah,
                                                     const ushort* __restrict__ Al,
                                                     const ushort* __restrict__ Bh,
                                                     const ushort* __restrict__ Bl,
                                                     const float* __restrict__ dis,
                                                     ushort* __restrict__ C, int M) {
    int gw = blockIdx.x * 4 + (threadIdx.x >> 6);
    int lane = threadIdx.x & 63;
    int wr = gw >> 1, wc = gw & 1;
    int row0 = wr * 64, col0 = wc * 128;
    if (row0 >= M) return;
    int lrow = lane & 15, lk = (lane >> 4) * 8;

    f32x4 acc[4][8];
#pragma unroll
    for (int i = 0; i < 4; ++i)
#pragma unroll
        for (int j = 0; j < 8; ++j) acc[i][j] = (f32x4)0.f;

#pragma unroll
    for (int ks = 0; ks < 8; ++ks) {
        int kb = ks * 32 + lk;
        bf16x8 ah[4], al[4];
#pragma unroll
        for (int i = 0; i < 4; ++i) {
            int row = row0 + i * 16 + lrow;
            if (row < M) {
                ah[i] = *(const bf16x8*)&Ah[(size_t)row * 256 + kb];
                al[i] = *(const bf16x8*)&Al[(size_t)row * 256 + kb];
            } else {
                ah[i] = (bf16x8)(short)0;
                al[i] = (bf16x8)(short)0;
            }
        }
#pragma unroll
        for (int j = 0; j < 8; ++j) {
            bf16x8 bh = *(const bf16x8*)&Bh[(size_t)(col0 + j * 16 + lrow) * 256 + kb];
            bf16x8 bl = *(const bf16x8*)&Bl[(size_t)(col0 + j * 16 + lrow) * 256 + kb];
#pragma unroll
            for (int i = 0; i < 4; ++i) {
                acc[i][j] = __builtin_amdgcn_mfma_f32_16x16x32_bf16(ah[i], bh, acc[i][j], 0, 0, 0);
                acc[i][j] = __builtin_amdgcn_mfma_f32_16x16x32_bf16(ah[i], bl, acc[i][j], 0, 0, 0);
                acc[i][j] = __builtin_amdgcn_mfma_f32_16x16x32_bf16(al[i], bh, acc[i][j], 0, 0, 0);
            }
        }
    }
    // C/D layout (m89): col = lane&15, row = (lane>>4)*4 + reg
    int rb = (lane >> 4) * 4;
#pragma unroll
    for (int i = 0; i < 4; ++i) {
#pragma unroll
        for (int r = 0; r < 4; ++r) {
            int row = row0 + i * 16 + rb + r;
            if (row >= M) continue;
            float dr = dis[row];
#pragma unroll
            for (int j = 0; j < 8; ++j) {
                int col = col0 + j * 16 + lrow;
                C[(size_t)row * 256 + col] = f2bf(dr * acc[i][j][r]);
            }
        }
    }
}

// ---------------- aggregate: out[n] = dis[n]*(T'[n] + sum_e T'[src_e]) + b ----------------
// one wave per node; lane covers 4 cols (8 B gather). Edge indices batch-loaded
// (64 per coalesced load), broadcast via readlane; x4 unroll, 4 indep accumulators.
// mode 1: PReLU + write hi/lo bf16 planes. mode 0: write fp32.
__global__ __launch_bounds__(256) void aggregate2(const ushort* __restrict__ Tp,
                                                  const int* __restrict__ row_ptr,
                                                  const int* __restrict__ csr_src,
                                                  const float* __restrict__ dis,
                                                  const float* __restrict__ bias,
                                                  const float* __restrict__ alpha_p,
                                                  float* __restrict__ outf,
                                                  ushort* __restrict__ outh,
                                                  ushort* __restrict__ outl,
                                                  int N, int mode) {
    int wave = threadIdx.x >> 6;
    int lane = threadIdx.x & 63;
    int n = blockIdx.x * 4 + wave;
    if (n >= N) return;
    int c = lane * 4;

    ushort4 sv = *(const ushort4*)&Tp[(size_t)n * 256 + c];
    float ax0 = bf2f(sv.x), ay0 = bf2f(sv.y), az0 = bf2f(sv.z), aw0 = bf2f(sv.w);
    float ax1 = 0.f, ay1 = 0.f, az1 = 0.f, aw1 = 0.f;
    float ax2 = 0.f, ay2 = 0.f, az2 = 0.f, aw2 = 0.f;
    float ax3 = 0.f, ay3 = 0.f, az3 = 0.f, aw3 = 0.f;

    int e0 = row_ptr[n], e1 = row_ptr[n + 1];
    for (int base = e0; base < e1; base += 64) {
        int rem = e1 - base;
        int m = rem < 64 ? rem : 64;
        int idx = csr_src[base + (lane < m ? lane : 0)];
        int j = 0;
        for (; j + 4 <= m; j += 4) {
            int s0 = __builtin_amdgcn_readlane(idx, j);
            int s1 = __builtin_amdgcn_readlane(idx, j + 1);
            int s2 = __builtin_amdgcn_readlane(idx, j + 2);
            int s3 = __builtin_amdgcn_readlane(idx, j + 3);
            ushort4 v0 = *(const ushort4*)&Tp[(size_t)s0 * 256 + c];
            ushort4 v1 = *(const ushort4*)&Tp[(size_t)s1 * 256 + c];
            ushort4 v2 = *(const ushort4*)&Tp[(size_t)s2 * 256 + c];
            ushort4 v3 = *(const ushort4*)&Tp[(size_t)s3 * 256 + c];
            ax0 += bf2f(v0.x); ay0 += bf2f(v0.y); az0 += bf2f(v0.z); aw0 += bf2f(v0.w);
            ax1 += bf2f(v1.x); ay1 += bf2f(v1.y); az1 += bf2f(v1.z); aw1 += bf2f(v1.w);
            ax2 += bf2f(v2.x); ay2 += bf2f(v2.y); az2 += bf2f(v2.z); aw2 += bf2f(v2.w);
            ax3 += bf2f(v3.x); ay3 += bf2f(v3.y); az3 += bf2f(v3.z); aw3 += bf2f(v3.w);
        }
        for (; j < m; ++j) {
            int s = __builtin_amdgcn_readlane(idx, j);
            ushort4 v = *(const ushort4*)&Tp[(size_t)s * 256 + c];
            ax0 += bf2f(v.x); ay0 += bf2f(v.y); az0 += bf2f(v.z); aw0 += bf2f(v.w);
        }
    }
    float dn = dis[n];
    float4 bv = *(const float4*)&bias[c];
    float rx = dn * (ax0 + ax1 + ax2 + ax3) + bv.x;
    float ry = dn * (ay0 + ay1 + ay2 + ay3) + bv.y;
    float rz = dn * (az0 + az1 + az2 + az3) + bv.z;
    float rw = dn * (aw0 + aw1 + aw2 + aw3) + bv.w;
    if (mode) {
        float al = *alpha_p;
        rx = rx >= 0.f ? rx : al * rx;
        ry = ry >= 0.f ? ry : al * ry;
        rz = rz >= 0.f ? rz : al * rz;
        rw = rw >= 0.f ? rw : al * rw;
        ushort hx = f2bf(rx), hy = f2bf(ry), hz = f2bf(rz), hw = f2bf(rw);
        *(ushort4*)&outh[(size_t)n * 256 + c] = make_ushort4(hx, hy, hz, hw);
        *(ushort4*)&outl[(size_t)n * 256 + c] = make_ushort4(f2bf(rx - bf2f(hx)), f2bf(ry - bf2f(hy)),
                                                             f2bf(rz - bf2f(hz)), f2bf(rw - bf2f(hw)));
    } else {
        *(float4*)&outf[(size_t)n * 256 + c] = make_float4(rx, ry, rz, rw);
    }
}

extern "C" void kernel_launch(void* const* d_in, const int* in_sizes, int n_in,
                              void* d_out, int out_size, void* d_ws, size_t ws_size,
                              hipStream_t stream) {
    const float* x = (const float*)d_in[0];
    const int* ei = (const int*)d_in[1];          // int32 (harness converts int64 -> int32)
    const float* W1 = (const float*)d_in[2];
    const float* b1 = (const float*)d_in[3];
    const float* W2 = (const float*)d_in[4];
    const float* b2 = (const float*)d_in[5];
    const float* alpha = (const float*)d_in[6];
    int N = in_sizes[0] / IN_C;
    int E = in_sizes[1] / 2;

    // ---- workspace layout (~116.4 MB, fits proven >=116.8 MB) ----
    char* ws = (char*)d_ws;
    size_t off = 0;
    auto alloc = [&](size_t bytes) {
        void* p = ws + off;
        off = (off + bytes + 255) & ~(size_t)255;
        return p;
    };
    int* cnt      = (int*)alloc((size_t)N * 4);        // doubles as cursor after scanA
    int* row_ptr  = (int*)alloc(((size_t)N + 1) * 4);
    int* partials = (int*)alloc(1024 * 4);
    float* dis    = (float*)alloc((size_t)N * 4);
    int* csr_src  = (int*)alloc((size_t)E * 4);
    ushort* Tp    = (ushort*)alloc((size_t)N * IN_C * 2);   // 51.2 MB
    ushort* Xl    = (ushort*)alloc((size_t)N * IN_C * 2);   // 51.2 MB (also Hl)
    if (off > ws_size) return;   // clean fail instead of fault if ws too small

    // ---- d_out doubles as scratch for dead-before-final-write planes ----
    // [0, 51.2MB): Xh then Hh.  [51.2MB, 51.7MB): W split tables.
    char* dob = (char*)d_out;
    ushort* Xh  = (ushort*)dob;                                   // also Hh
    ushort* W1h = (ushort*)(dob + (size_t)N * IN_C * 2);
    ushort* W1l = W1h + 65536;
    ushort* W2h = W1h + 131072;
    ushort* W2l = W1h + 196608;
    float* outf = (float*)d_out;

    hipMemsetAsync(cnt, 0, (size_t)N * 4, stream);

    int eb = (E + 255) / 256;
    int nb256 = (N + 255) / 256;
    int nb1024 = (N + 1023) / 1024;

    count_kernel<<<eb, 256, 0, stream>>>(ei, cnt, E);
    dis_kernel<<<nb256, 256, 0, stream>>>(cnt, dis, N);
    scanA<<<nb1024, 256, 0, stream>>>(cnt, row_ptr, partials, N);
    scanB<<<1, 64, 0, stream>>>(partials, row_ptr, nb1024, N);
    scanC<<<nb256, 256, 0, stream>>>(row_ptr, cnt /*cursor*/, partials, N);
    fill_kernel<<<eb, 256, 0, stream>>>(ei, cnt /*cursor*/, csr_src, E);

    int total4 = N * (IN_C / 4);
    split_x<<<(total4 + 255) / 256, 256, 0, stream>>>(x, Xh, Xl, total4);
    prep_w<<<256, 256, 0, stream>>>(W1, W1h, W1l);
    prep_w<<<256, 256, 0, stream>>>(W2, W2h, W2l);

    int nrow_t = (N + 63) / 64;
    int gblocks = (nrow_t * 2 + 3) / 4;
    int ablocks = (N + 3) / 4;

    // layer 1: T' = dis * (x@W1);  H(hi/lo) = prelu(dn*(T'n + sum T's) + b1)
    gemm_split<<<gblocks, 256, 0, stream>>>(Xh, Xl, W1h, W1l, dis, Tp, N);
    aggregate2<<<ablocks, 256, 0, stream>>>(Tp, row_ptr, csr_src, dis, b1, alpha,
                                            nullptr, Xh /*Hh*/, Xl /*Hl*/, N, 1);
    // layer 2: T' = dis * (H@W2);  out = dn*(T'n + sum T's) + b2
    gemm_split<<<gblocks, 256, 0, stream>>>(Xh /*Hh*/, Xl /*Hl*/, W2h, W2l, dis, Tp, N);
    aggregate2<<<ablocks, 256, 0, stream>>>(Tp, row_ptr, csr_src, dis, b2, alpha,
                                            outf, nullptr, nullptr, N, 0);
}

// Round 6
// 809.167 us; speedup vs baseline: 2.1123x; 1.3874x over previous
//
#include <hip/hip_runtime.h>
#include <cstdint>
#include <cstddef>

// -------- GCN 2-layer: out = A_norm @ prelu(A_norm @ (x W1) + b1) @ W2 + b2 --------
// A_norm = D^-1/2 (A + I) D^-1/2, deg = in-degree + 1 (PyG GCNConv default).
// edge_index arrives int32 [2][E]: src = ei[e], dst = ei[E + e].
//
// Round 6: CSR build rewritten as a two-level bucketed sort to kill the random-
// scatter write amplification (fill_kernel wrote 194 MB HBM for a 12.8 MB array):
//  passA: per-block LDS histogram by dst>>9, run-reservation via one global atomic
//         per (block,bucket), (src,dst) pairs written in ~168B contiguous runs.
//  passB: one block per bucket; local CSR (512 LDS counters + scan); csr_src
//         scatter confined to the bucket's ~96KB window -> L2-aggregated writes.
//  deg/dis derived from row_ptr diffs (count_kernel + scans removed).
// GEMM: no-LDS MFMA, hi/lo bf16 split (~fp32 accuracy), dis folded into epilogue.
// Aggregate: pure row-sum, 64-edge batched index loads + readlane broadcast, x4 ILP.
// bucketBuf aliases Tp (dead until gemm1). ws ~116 MB.

#define IN_C 256
#define BSHIFT 9
#define BCAP 24576   // bucket capacity (avg ~16.3K edges/bucket; huge margin)

typedef __attribute__((ext_vector_type(8))) short bf16x8;
typedef __attribute__((ext_vector_type(4))) float f32x4;

__device__ __forceinline__ ushort f2bf(float x) {
    union { float f; uint32_t u; } v; v.f = x;
    uint32_t r = v.u + 0x7FFF + ((v.u >> 16) & 1);   // round-to-nearest-even
    return (ushort)(r >> 16);
}
__device__ __forceinline__ float bf2f(ushort b) {
    union { uint32_t u; float f; } v; v.u = ((uint32_t)b) << 16;
    return v.f;
}

// ---------------- CSR build: passA (bucket scatter, 4096 edges/block) ----------------
__global__ __launch_bounds__(256) void passA(const int* __restrict__ ei,
                                             int* __restrict__ bucketCnt,
                                             int2* __restrict__ bucketBuf, int E, int NB) {
    __shared__ int hist[256];
    __shared__ int gbase[256];
    __shared__ int cur[256];
    int tid = threadIdx.x;
    hist[tid] = 0; cur[tid] = 0;
    __syncthreads();
    int e0 = blockIdx.x * 4096;
    int src_r[16], dst_r[16];
#pragma unroll
    for (int i = 0; i < 16; ++i) {
        int e = e0 + i * 256 + tid;
        if (e < E) {
            src_r[i] = ei[e];
            dst_r[i] = ei[(size_t)E + e];
            atomicAdd(&hist[dst_r[i] >> BSHIFT], 1);
        } else dst_r[i] = -1;
    }
    __syncthreads();
    if (tid < NB && hist[tid] > 0) gbase[tid] = atomicAdd(&bucketCnt[tid], hist[tid]);
    __syncthreads();
#pragma unroll
    for (int i = 0; i < 16; ++i) {
        if (dst_r[i] >= 0) {
            int b = dst_r[i] >> BSHIFT;
            int p = atomicAdd(&cur[b], 1);
            int pos = gbase[b] + p;
            if (pos < BCAP) bucketBuf[(size_t)b * BCAP + pos] = make_int2(src_r[i], dst_r[i]);
        }
    }
}

// ---------------- CSR build: bucket base scan (tiny) ----------------
__global__ void bucket_scan(const int* __restrict__ bucketCnt, int* __restrict__ bucket_base,
                            int* __restrict__ row_ptr, int NB, int N) {
    if (threadIdx.x == 0 && blockIdx.x == 0) {
        int run = 0;
        for (int b = 0; b < NB; ++b) {
            int c = bucketCnt[b]; if (c > BCAP) c = BCAP;
            bucket_base[b] = run; run += c;
        }
        row_ptr[N] = run;   // == E
    }
}

// ---------------- CSR build: passB (one block per bucket; local CSR in LDS) ----------------
__global__ __launch_bounds__(256) void passB(const int2* __restrict__ bucketBuf,
                                             const int* __restrict__ bucketCnt,
                                             const int* __restrict__ bucket_base,
                                             int* __restrict__ row_ptr,
                                             int* __restrict__ csr_src, int N) {
    __shared__ int cnt[512];
    __shared__ int ofs[512];
    __shared__ int ssum[256];
    int b = blockIdx.x, tid = threadIdx.x;
    int base_node = b << BSHIFT;
    int nnodes = N - base_node; if (nnodes > 512) nnodes = 512;
    int nE = bucketCnt[b]; if (nE > BCAP) nE = BCAP;
    const int2* buf = bucketBuf + (size_t)b * BCAP;
    cnt[tid] = 0; cnt[tid + 256] = 0;
    __syncthreads();
    for (int i = tid; i < nE; i += 256) {
        int2 p = buf[i];
        atomicAdd(&cnt[p.y - base_node], 1);
    }
    __syncthreads();
    int c0 = cnt[2 * tid], c1 = cnt[2 * tid + 1];
    int s = c0 + c1;
    ssum[tid] = s;
    __syncthreads();
    for (int o = 1; o < 256; o <<= 1) {
        int add = (tid >= o) ? ssum[tid - o] : 0;
        __syncthreads();
        ssum[tid] += add;
        __syncthreads();
    }
    int run = ssum[tid] - s;           // exclusive within bucket
    int gb = bucket_base[b];
    int o0 = gb + run, o1 = gb + run + c0;
    ofs[2 * tid] = o0; ofs[2 * tid + 1] = o1;
    if (2 * tid < nnodes)     row_ptr[base_node + 2 * tid]     = o0;
    if (2 * tid + 1 < nnodes) row_ptr[base_node + 2 * tid + 1] = o1;
    __syncthreads();
    for (int i = tid; i < nE; i += 256) {
        int2 p = buf[i];
        int pos = atomicAdd(&ofs[p.y - base_node], 1);
        csr_src[pos] = p.x;            // ~96KB window: L2-aggregated writeback
    }
}

// ---------------- dis from row_ptr diffs ----------------
__global__ __launch_bounds__(256) void dis2(const int* __restrict__ row_ptr,
                                            float* __restrict__ dis, int N) {
    int i = blockIdx.x * 256 + threadIdx.x;
    if (i < N) dis[i] = rsqrtf((float)(row_ptr[i + 1] - row_ptr[i] + 1));
}

// ---------------- split fp32 -> hi/lo bf16 planes ----------------
__global__ __launch_bounds__(256) void split_x(const float* __restrict__ x,
                                               ushort* __restrict__ Xh,
                                               ushort* __restrict__ Xl, int total4) {
    int id = blockIdx.x * 256 + threadIdx.x;   // unit = 4 floats
    if (id >= total4) return;
    float4 v = ((const float4*)x)[id];
    ushort hx = f2bf(v.x), hy = f2bf(v.y), hz = f2bf(v.z), hw = f2bf(v.w);
    ((ushort4*)Xh)[id] = make_ushort4(hx, hy, hz, hw);
    ((ushort4*)Xl)[id] = make_ushort4(f2bf(v.x - bf2f(hx)), f2bf(v.y - bf2f(hy)),
                                      f2bf(v.z - bf2f(hz)), f2bf(v.w - bf2f(hw)));
}

// ---------------- weight prep: W[k][n] f32 -> WT[n][k] hi/lo bf16 ----------------
__global__ __launch_bounds__(256) void prep_w(const float* __restrict__ W,
                                              ushort* __restrict__ WTh,
                                              ushort* __restrict__ WTl) {
    int id = blockIdx.x * 256 + threadIdx.x;   // 65536
    int n = id >> 8, k = id & 255;
    float w = W[k * 256 + n];
    ushort h = f2bf(w);
    WTh[id] = h;
    WTl[id] = f2bf(w - bf2f(h));
}

// ---------------- no-LDS MFMA GEMM: T'(bf16)[M][256] = dis[r] * (A @ W) ----------------
__global__ __launch_bounds__(256, 2) void gemm_split(const ushort* __restrict__ Ah,
                                                     const ushort* __restrict__ Al,
                                                     const ushort* __restrict__ Bh,
                                                     const ushort* __restrict__ Bl,
                                                     const float* __restrict__ dis,
                                                     ushort* __restrict__ C, int M) {
    int gw = blockIdx.x * 4 + (threadIdx.x >> 6);
    int lane = threadIdx.x & 63;
    int wr = gw >> 1, wc = gw & 1;
    int row0 = wr * 64, col0 = wc * 128;
    if (row0 >= M) return;
    int lrow = lane & 15, lk = (lane >> 4) * 8;

    f32x4 acc[4][8];
#pragma unroll
    for (int i = 0; i < 4; ++i)
#pragma unroll
        for (int j = 0; j < 8; ++j) acc[i][j] = (f32x4)0.f;

#pragma unroll
    for (int ks = 0; ks < 8; ++ks) {
        int kb = ks * 32 + lk;
        bf16x8 ah[4], al[4];
#pragma unroll
        for (int i = 0; i < 4; ++i) {
            int row = row0 + i * 16 + lrow;
            if (row < M) {
                ah[i] = *(const bf16x8*)&Ah[(size_t)row * 256 + kb];
                al[i] = *(const bf16x8*)&Al[(size_t)row * 256 + kb];
            } else {
                ah[i] = (bf16x8)(short)0;
                al[i] = (bf16x8)(short)0;
            }
        }
#pragma unroll
        for (int j = 0; j < 8; ++j) {
            bf16x8 bh = *(const bf16x8*)&Bh[(size_t)(col0 + j * 16 + lrow) * 256 + kb];
            bf16x8 bl = *(const bf16x8*)&Bl[(size_t)(col0 + j * 16 + lrow) * 256 + kb];
#pragma unroll
            for (int i = 0; i < 4; ++i) {
                acc[i][j] = __builtin_amdgcn_mfma_f32_16x16x32_bf16(ah[i], bh, acc[i][j], 0, 0, 0);
                acc[i][j] = __builtin_amdgcn_mfma_f32_16x16x32_bf16(ah[i], bl, acc[i][j], 0, 0, 0);
                acc[i][j] = __builtin_amdgcn_mfma_f32_16x16x32_bf16(al[i], bh, acc[i][j], 0, 0, 0);
            }
        }
    }
    // C/D layout (m89): col = lane&15, row = (lane>>4)*4 + reg
    int rb = (lane >> 4) * 4;
#pragma unroll
    for (int i = 0; i < 4; ++i) {
#pragma unroll
        for (int r = 0; r < 4; ++r) {
            int row = row0 + i * 16 + rb + r;
            if (row >= M) continue;
            float dr = dis[row];
#pragma unroll
            for (int j = 0; j < 8; ++j) {
                int col = col0 + j * 16 + lrow;
                C[(size_t)row * 256 + col] = f2bf(dr * acc[i][j][r]);
            }
        }
    }
}

// ---------------- aggregate: out[n] = dis[n]*(T'[n] + sum_e T'[src_e]) + b ----------------
__global__ __launch_bounds__(256) void aggregate2(const ushort* __restrict__ Tp,
                                                  const int* __restrict__ row_ptr,
                                                  const int* __restrict__ csr_src,
                                                  const float* __restrict__ dis,
                                                  const float* __restrict__ bias,
                                                  const float* __restrict__ alpha_p,
                                                  float* __restrict__ outf,
                                                  ushort* __restrict__ outh,
                                                  ushort* __restrict__ outl,
                                                  int N, int mode) {
    int wave = threadIdx.x >> 6;
    int lane = threadIdx.x & 63;
    int n = blockIdx.x * 4 + wave;
    if (n >= N) return;
    int c = lane * 4;

    ushort4 sv = *(const ushort4*)&Tp[(size_t)n * 256 + c];
    float ax0 = bf2f(sv.x), ay0 = bf2f(sv.y), az0 = bf2f(sv.z), aw0 = bf2f(sv.w);
    float ax1 = 0.f, ay1 = 0.f, az1 = 0.f, aw1 = 0.f;
    float ax2 = 0.f, ay2 = 0.f, az2 = 0.f, aw2 = 0.f;
    float ax3 = 0.f, ay3 = 0.f, az3 = 0.f, aw3 = 0.f;

    int e0 = row_ptr[n], e1 = row_ptr[n + 1];
    for (int base = e0; base < e1; base += 64) {
        int rem = e1 - base;
        int m = rem < 64 ? rem : 64;
        int idx = csr_src[base + (lane < m ? lane : 0)];
        int j = 0;
        for (; j + 4 <= m; j += 4) {
            int s0 = __builtin_amdgcn_readlane(idx, j);
            int s1 = __builtin_amdgcn_readlane(idx, j + 1);
            int s2 = __builtin_amdgcn_readlane(idx, j + 2);
            int s3 = __builtin_amdgcn_readlane(idx, j + 3);
            ushort4 v0 = *(const ushort4*)&Tp[(size_t)s0 * 256 + c];
            ushort4 v1 = *(const ushort4*)&Tp[(size_t)s1 * 256 + c];
            ushort4 v2 = *(const ushort4*)&Tp[(size_t)s2 * 256 + c];
            ushort4 v3 = *(const ushort4*)&Tp[(size_t)s3 * 256 + c];
            ax0 += bf2f(v0.x); ay0 += bf2f(v0.y); az0 += bf2f(v0.z); aw0 += bf2f(v0.w);
            ax1 += bf2f(v1.x); ay1 += bf2f(v1.y); az1 += bf2f(v1.z); aw1 += bf2f(v1.w);
            ax2 += bf2f(v2.x); ay2 += bf2f(v2.y); az2 += bf2f(v2.z); aw2 += bf2f(v2.w);
            ax3 += bf2f(v3.x); ay3 += bf2f(v3.y); az3 += bf2f(v3.z); aw3 += bf2f(v3.w);
        }
        for (; j < m; ++j) {
            int s = __builtin_amdgcn_readlane(idx, j);
            ushort4 v = *(const ushort4*)&Tp[(size_t)s * 256 + c];
            ax0 += bf2f(v.x); ay0 += bf2f(v.y); az0 += bf2f(v.z); aw0 += bf2f(v.w);
        }
    }
    float dn = dis[n];
    float4 bv = *(const float4*)&bias[c];
    float rx = dn * (ax0 + ax1 + ax2 + ax3) + bv.x;
    float ry = dn * (ay0 + ay1 + ay2 + ay3) + bv.y;
    float rz = dn * (az0 + az1 + az2 + az3) + bv.z;
    float rw = dn * (aw0 + aw1 + aw2 + aw3) + bv.w;
    if (mode) {
        float al = *alpha_p;
        rx = rx >= 0.f ? rx : al * rx;
        ry = ry >= 0.f ? ry : al * ry;
        rz = rz >= 0.f ? rz : al * rz;
        rw = rw >= 0.f ? rw : al * rw;
        ushort hx = f2bf(rx), hy = f2bf(ry), hz = f2bf(rz), hw = f2bf(rw);
        *(ushort4*)&outh[(size_t)n * 256 + c] = make_ushort4(hx, hy, hz, hw);
        *(ushort4*)&outl[(size_t)n * 256 + c] = make_ushort4(f2bf(rx - bf2f(hx)), f2bf(ry - bf2f(hy)),
                                                             f2bf(rz - bf2f(hz)), f2bf(rw - bf2f(hw)));
    } else {
        *(float4*)&outf[(size_t)n * 256 + c] = make_float4(rx, ry, rz, rw);
    }
}

extern "C" void kernel_launch(void* const* d_in, const int* in_sizes, int n_in,
                              void* d_out, int out_size, void* d_ws, size_t ws_size,
                              hipStream_t stream) {
    const float* x = (const float*)d_in[0];
    const int* ei = (const int*)d_in[1];          // int32 (harness converts int64 -> int32)
    const float* W1 = (const float*)d_in[2];
    const float* b1 = (const float*)d_in[3];
    const float* W2 = (const float*)d_in[4];
    const float* b2 = (const float*)d_in[5];
    const float* alpha = (const float*)d_in[6];
    int N = in_sizes[0] / IN_C;
    int E = in_sizes[1] / 2;
    int NB = (N + 511) >> BSHIFT;
    if (NB > 256) return;                          // clean fail on unexpected N

    // ---- workspace layout (~116 MB, within proven footprint) ----
    char* ws = (char*)d_ws;
    size_t off = 0;
    auto alloc = [&](size_t bytes) {
        void* p = ws + off;
        off = (off + bytes + 255) & ~(size_t)255;
        return p;
    };
    int* row_ptr     = (int*)alloc(((size_t)N + 1) * 4);
    float* dis       = (float*)alloc((size_t)N * 4);
    int* csr_src     = (int*)alloc((size_t)E * 4);
    int* bucketCnt   = (int*)alloc(256 * 4);
    int* bucket_base = (int*)alloc(256 * 4);
    ushort* Tp       = (ushort*)alloc((size_t)N * IN_C * 2);   // 51.2 MB (bucketBuf alias)
    ushort* Xl       = (ushort*)alloc((size_t)N * IN_C * 2);   // 51.2 MB (also Hl)
    if (off > ws_size) return;                     // clean fail if ws too small
    int2* bucketBuf = (int2*)Tp;                   // dead before gemm1 writes Tp
    if ((size_t)NB * BCAP * 8 > (size_t)N * IN_C * 2) return;  // alias capacity guard

    // ---- d_out doubles as scratch (dead before final write) ----
    char* dob = (char*)d_out;
    ushort* Xh  = (ushort*)dob;                                   // also Hh
    ushort* W1h = (ushort*)(dob + (size_t)N * IN_C * 2);
    ushort* W1l = W1h + 65536;
    ushort* W2h = W1h + 131072;
    ushort* W2l = W1h + 196608;
    float* outf = (float*)d_out;

    hipMemsetAsync(bucketCnt, 0, 256 * 4, stream);

    // ---- CSR build (bucketed) ----
    passA<<<(E + 4095) / 4096, 256, 0, stream>>>(ei, bucketCnt, bucketBuf, E, NB);
    bucket_scan<<<1, 64, 0, stream>>>(bucketCnt, bucket_base, row_ptr, NB, N);
    passB<<<NB, 256, 0, stream>>>(bucketBuf, bucketCnt, bucket_base, row_ptr, csr_src, N);
    int nb256 = (N + 255) / 256;
    dis2<<<nb256, 256, 0, stream>>>(row_ptr, dis, N);

    // ---- precision prep ----
    int total4 = N * (IN_C / 4);
    split_x<<<(total4 + 255) / 256, 256, 0, stream>>>(x, Xh, Xl, total4);
    prep_w<<<256, 256, 0, stream>>>(W1, W1h, W1l);
    prep_w<<<256, 256, 0, stream>>>(W2, W2h, W2l);

    int nrow_t = (N + 63) / 64;
    int gblocks = (nrow_t * 2 + 3) / 4;
    int ablocks = (N + 3) / 4;

    // layer 1: T' = dis * (x@W1);  H(hi/lo) = prelu(dn*(T'n + sum T's) + b1)
    gemm_split<<<gblocks, 256, 0, stream>>>(Xh, Xl, W1h, W1l, dis, Tp, N);
    aggregate2<<<ablocks, 256, 0, stream>>>(Tp, row_ptr, csr_src, dis, b1, alpha,
                                            nullptr, Xh /*Hh*/, Xl /*Hl*/, N, 1);
    // layer 2: T' = dis * (H@W2);  out = dn*(T'n + sum T's) + b2
    gemm_split<<<gblocks, 256, 0, stream>>>(Xh /*Hh*/, Xl /*Hl*/, W2h, W2l, dis, Tp, N);
    aggregate2<<<ablocks, 256, 0, stream>>>(Tp, row_ptr, csr_src, dis, b2, alpha,
                                            outf, nullptr, nullptr, N, 0);
}